// Round 1
// baseline (302.016 us; speedup 1.0000x reference)
//
#include <hip/hip_runtime.h>

using f32x4  = __attribute__((ext_vector_type(4))) float;
using short8 = __attribute__((ext_vector_type(8))) short;
using u16    = unsigned short;

#define B_SZ   2
#define S_LEN  2048
#define NH     16
#define NKV    4
#define DH     64
#define DM     1024
#define NQKVC  1536
#define MROWS  4096
#define ATT_SCALE 0.125f

__device__ __forceinline__ u16 f2bf(float f) {
  unsigned int u = __builtin_bit_cast(unsigned int, f);
  u += 0x7fffu + ((u >> 16) & 1u);
  return (u16)(u >> 16);
}
__device__ __forceinline__ float bf2f(u16 b) {
  unsigned int u = ((unsigned int)b) << 16;
  return __builtin_bit_cast(float, u);
}

// ---------------- cast X fp32 -> bf16 ----------------
__global__ void k_cast_x(const float* __restrict__ x, u16* __restrict__ xb) {
  int i = (blockIdx.x * 256 + threadIdx.x) * 4;
  float4 v = *(const float4*)(x + i);
  ushort4 o;
  o.x = f2bf(v.x); o.y = f2bf(v.y); o.z = f2bf(v.z); o.w = f2bf(v.w);
  *(ushort4*)(xb + i) = o;
}

// ---------------- weight transpose: W[K=1024][ncols] fp32 -> Wt[n][1024] bf16 ----------------
__global__ void k_transpose_w(const float* __restrict__ w, int ncols, u16* __restrict__ wt) {
  __shared__ float t[32][33];
  int k0 = blockIdx.x * 32, n0 = blockIdx.y * 32;
  int tx = threadIdx.x, ty = threadIdx.y; // block (32,8)
#pragma unroll
  for (int j = 0; j < 32; j += 8)
    t[ty + j][tx] = w[(size_t)(k0 + ty + j) * ncols + n0 + tx];
  __syncthreads();
#pragma unroll
  for (int j = 0; j < 32; j += 8)
    wt[(size_t)(n0 + ty + j) * 1024 + k0 + tx] = f2bf(t[tx][ty + j]);
}

// ---------------- bias concat + trig tables ----------------
__global__ void k_prep_small(const float* __restrict__ bq, const float* __restrict__ bk,
                             const float* __restrict__ bv, const float* __restrict__ pe,
                             float* __restrict__ biasqkv, float* __restrict__ cs,
                             float* __restrict__ sn) {
  int i = blockIdx.x * 256 + threadIdx.x;
  if (i < NQKVC)
    biasqkv[i] = (i < 1024) ? bq[i] : (i < 1280 ? bk[i - 1024] : bv[i - 1280]);
  if (i < S_LEN * 32) {
    float a = pe[i];
    cs[i] = cosf(a);
    sn[i] = sinf(a);
  }
}

// ---------------- bf16 MFMA GEMM: C[M][N] = A[M][K] @ Bt[N][K]^T + bias ----------------
template <typename OUT_T>
__global__ __launch_bounds__(256) void k_gemm(const u16* __restrict__ A,
                                              const u16* __restrict__ Bt,
                                              const float* __restrict__ bias,
                                              OUT_T* __restrict__ C,
                                              int M, int N, int K) {
  __shared__ u16 la[128][40];  // stride 40 elems = 80B -> 2-way bank aliasing only
  __shared__ u16 lb[128][40];
  const int tid = threadIdx.x;
  const int m0 = blockIdx.x * 128, n0 = blockIdx.y * 128;
  const int lane = tid & 63, wv = tid >> 6;
  const int g = lane >> 4, lr = lane & 15;
  const int wr = wv >> 1, wc = wv & 1;

  // staging: 512 chunks of 8 bf16 per matrix; 2 per thread
  const int c0 = tid, c1 = tid + 256;
  const int r0 = c0 >> 2, kc0 = (c0 & 3) * 8;
  const int r1 = c1 >> 2, kc1 = (c1 & 3) * 8;
  const u16* pa0 = A  + (size_t)(m0 + r0) * K + kc0;
  const u16* pa1 = A  + (size_t)(m0 + r1) * K + kc1;
  const u16* pb0 = Bt + (size_t)(n0 + r0) * K + kc0;
  const u16* pb1 = Bt + (size_t)(n0 + r1) * K + kc1;

  f32x4 acc[4][4] = {};

  short8 ra0 = *(const short8*)pa0;
  short8 ra1 = *(const short8*)pa1;
  short8 rb0 = *(const short8*)pb0;
  short8 rb1 = *(const short8*)pb1;

  const int nk = K >> 5;
  for (int kt = 0; kt < nk; ++kt) {
    __syncthreads();
    *(short8*)&la[r0][kc0] = ra0;
    *(short8*)&la[r1][kc1] = ra1;
    *(short8*)&lb[r0][kc0] = rb0;
    *(short8*)&lb[r1][kc1] = rb1;
    __syncthreads();
    if (kt + 1 < nk) {
      const int ko = (kt + 1) << 5;
      ra0 = *(const short8*)(pa0 + ko);
      ra1 = *(const short8*)(pa1 + ko);
      rb0 = *(const short8*)(pb0 + ko);
      rb1 = *(const short8*)(pb1 + ko);
    }
    short8 af[4], bfr[4];
#pragma unroll
    for (int m = 0; m < 4; ++m) af[m]  = *(const short8*)&la[64 * wr + 16 * m + lr][8 * g];
#pragma unroll
    for (int n = 0; n < 4; ++n) bfr[n] = *(const short8*)&lb[64 * wc + 16 * n + lr][8 * g];
#pragma unroll
    for (int m = 0; m < 4; ++m)
#pragma unroll
      for (int n = 0; n < 4; ++n)
        acc[m][n] = __builtin_amdgcn_mfma_f32_16x16x32_bf16(af[m], bfr[n], acc[m][n], 0, 0, 0);
  }

#pragma unroll
  for (int m = 0; m < 4; ++m)
#pragma unroll
    for (int n = 0; n < 4; ++n) {
      const int col = n0 + 64 * wc + 16 * n + lr;
      const float bz = bias[col];
#pragma unroll
      for (int r = 0; r < 4; ++r) {
        const int row = m0 + 64 * wr + 16 * m + 4 * g + r;
        float v = acc[m][n][r] + bz;
        if constexpr (sizeof(OUT_T) == 2) C[(size_t)row * N + col] = f2bf(v);
        else                              C[(size_t)row * N + col] = v;
      }
    }
}

// ---------------- RoPE + layout pack ----------------
// QKVp bf16 [4096][1536] -> Qr[B][H][S][64], Kr[B][Kv][S][64], Vt[B][Kv][64][S]
__global__ void k_rope_pack(const u16* __restrict__ p, const float* __restrict__ cs,
                            const float* __restrict__ sn, u16* __restrict__ Qr,
                            u16* __restrict__ Kr, u16* __restrict__ Vt) {
  int i = blockIdx.x * 256 + threadIdx.x;  // 0 .. 4096*1536
  int row = i / NQKVC;
  int c = i - row * NQKVC;
  int b = row >> 11, s = row & 2047;
  if (c < 1024) {
    int h = c >> 6, d = c & 63, j = d & 31;
    float x = bf2f(p[i]);
    float y = bf2f(p[i ^ 32]);  // partner d^32 within same head
    float o = x * cs[s * 32 + j] + (d < 32 ? -y : y) * sn[s * 32 + j];
    Qr[((size_t)(b * NH + h) * S_LEN + s) * DH + d] = f2bf(o);
  } else if (c < 1280) {
    int cc = c - 1024;
    int kv = cc >> 6, d = cc & 63, j = d & 31;
    float x = bf2f(p[i]);
    float y = bf2f(p[i ^ 32]);
    float o = x * cs[s * 32 + j] + (d < 32 ? -y : y) * sn[s * 32 + j];
    Kr[((size_t)(b * NKV + kv) * S_LEN + s) * DH + d] = f2bf(o);
  } else {
    int cc = c - 1280;
    int kv = cc >> 6, d = cc & 63;
    Vt[((size_t)(b * NKV + kv) * DH + d) * S_LEN + s] = p[i];
  }
}

// ---------------- causal GQA flash attention ----------------
// grid (B*H, S/64), block 256. Wave wv handles q rows [q0, q0+16).
__global__ __launch_bounds__(256) void k_attn(const u16* __restrict__ Qr,
                                              const u16* __restrict__ Kr,
                                              const u16* __restrict__ Vt,
                                              u16* __restrict__ Og) {
  __shared__ u16 plds[4][16][40];  // per-wave P tile (16 q x 32 k), padded stride
  const int tid = threadIdx.x, wv = tid >> 6, lane = tid & 63;
  const int g = lane >> 4, lr = lane & 15;
  const int bh = blockIdx.x;
  const int b = bh >> 4, h = bh & 15, kv = h >> 2;
  const int q0 = blockIdx.y * 64 + wv * 16;

  const u16* Qbase = Qr + ((size_t)(b * NH + h) * S_LEN + q0) * DH;
  const u16* Kbase = Kr + ((size_t)(b * NKV + kv) * S_LEN) * DH;
  const u16* Vbase = Vt + ((size_t)(b * NKV + kv) * DH) * S_LEN;

  short8 qf0 = *(const short8*)(Qbase + lr * DH + 8 * g);        // d in [0,32)
  short8 qf1 = *(const short8*)(Qbase + lr * DH + 32 + 8 * g);   // d in [32,64)

  float m[4]    = {-1e30f, -1e30f, -1e30f, -1e30f};
  float lsum[4] = {0.f, 0.f, 0.f, 0.f};
  f32x4 accO[4] = {};
  const f32x4 z = {};

  const int kend = q0 + 16;
  for (int kb = 0; kb < kend; kb += 32) {
    // K fragments: two 16-row k-subtiles x two d-halves
    short8 kf00 = *(const short8*)(Kbase + (size_t)(kb + lr) * DH + 8 * g);
    short8 kf01 = *(const short8*)(Kbase + (size_t)(kb + lr) * DH + 32 + 8 * g);
    short8 kf10 = *(const short8*)(Kbase + (size_t)(kb + 16 + lr) * DH + 8 * g);
    short8 kf11 = *(const short8*)(Kbase + (size_t)(kb + 16 + lr) * DH + 32 + 8 * g);

    f32x4 s0 = __builtin_amdgcn_mfma_f32_16x16x32_bf16(qf0, kf00, z, 0, 0, 0);
    s0 = __builtin_amdgcn_mfma_f32_16x16x32_bf16(qf1, kf01, s0, 0, 0, 0);
    f32x4 s1 = __builtin_amdgcn_mfma_f32_16x16x32_bf16(qf0, kf10, z, 0, 0, 0);
    s1 = __builtin_amdgcn_mfma_f32_16x16x32_bf16(qf1, kf11, s1, 0, 0, 0);

    float p0[4], p1[4], t[4];
    const bool msk = (kb + 31 > q0);
#pragma unroll
    for (int r = 0; r < 4; ++r) {
      float a = s0[r] * ATT_SCALE;
      float c = s1[r] * ATT_SCALE;
      if (msk) {
        int qg = q0 + 4 * g + r;
        if (kb + lr > qg)      a = -1e30f;
        if (kb + 16 + lr > qg) c = -1e30f;
      }
      p0[r] = a; p1[r] = c;
    }
    // row max across the 16-lane group
#pragma unroll
    for (int r = 0; r < 4; ++r) t[r] = fmaxf(p0[r], p1[r]);
#pragma unroll
    for (int off = 1; off < 16; off <<= 1)
#pragma unroll
      for (int r = 0; r < 4; ++r) t[r] = fmaxf(t[r], __shfl_xor(t[r], off));

    float alpha[4];
#pragma unroll
    for (int r = 0; r < 4; ++r) {
      float mn = fmaxf(m[r], t[r]);
      alpha[r] = __expf(m[r] - mn);
      m[r] = mn;
      p0[r] = __expf(p0[r] - mn);
      p1[r] = __expf(p1[r] - mn);
      t[r] = p0[r] + p1[r];
    }
#pragma unroll
    for (int off = 1; off < 16; off <<= 1)
#pragma unroll
      for (int r = 0; r < 4; ++r) t[r] += __shfl_xor(t[r], off);
#pragma unroll
    for (int r = 0; r < 4; ++r) lsum[r] = lsum[r] * alpha[r] + t[r];
#pragma unroll
    for (int n = 0; n < 4; ++n)
#pragma unroll
      for (int r = 0; r < 4; ++r) accO[n][r] *= alpha[r];

    // P (16x32) to LDS in D-layout, read back in A-fragment layout
#pragma unroll
    for (int r = 0; r < 4; ++r) {
      plds[wv][4 * g + r][lr]      = f2bf(p0[r]);
      plds[wv][4 * g + r][16 + lr] = f2bf(p1[r]);
    }
    short8 pa = *(const short8*)&plds[wv][lr][8 * g];

    short8 vb[4];
#pragma unroll
    for (int n = 0; n < 4; ++n)
      vb[n] = *(const short8*)(Vbase + (size_t)(lr + 16 * n) * S_LEN + kb + 8 * g);
#pragma unroll
    for (int n = 0; n < 4; ++n)
      accO[n] = __builtin_amdgcn_mfma_f32_16x16x32_bf16(pa, vb[n], accO[n], 0, 0, 0);
  }

#pragma unroll
  for (int n = 0; n < 4; ++n)
#pragma unroll
    for (int r = 0; r < 4; ++r) {
      int qg = q0 + 4 * g + r;
      Og[((size_t)(b * S_LEN + qg)) * DM + h * DH + lr + 16 * n] =
          f2bf(accO[n][r] / lsum[r]);
    }
}

extern "C" void kernel_launch(void* const* d_in, const int* in_sizes, int n_in,
                              void* d_out, int out_size, void* d_ws, size_t ws_size,
                              hipStream_t stream) {
  const float* x  = (const float*)d_in[0];
  const float* pe = (const float*)d_in[1];
  const float* Wq = (const float*)d_in[2];
  const float* bq = (const float*)d_in[3];
  const float* Wk = (const float*)d_in[4];
  const float* bk = (const float*)d_in[5];
  const float* Wv = (const float*)d_in[6];
  const float* bv = (const float*)d_in[7];
  const float* Wo = (const float*)d_in[8];
  const float* bo = (const float*)d_in[9];
  float* out = (float*)d_out;

  char* w = (char*)d_ws;
  u16* Xb      = (u16*)w;   w += (size_t)MROWS * DM * 2;        // 8 MB
  u16* Wqkvt   = (u16*)w;   w += (size_t)NQKVC * DM * 2;        // 3 MB
  u16* Wot     = (u16*)w;   w += (size_t)DM * DM * 2;           // 2 MB
  float* biasq = (float*)w; w += NQKVC * 4;                     // 6 KB
  float* cs    = (float*)w; w += S_LEN * 32 * 4;                // 256 KB
  float* sn    = (float*)w; w += S_LEN * 32 * 4;                // 256 KB
  u16* QKVp    = (u16*)w;   w += (size_t)MROWS * NQKVC * 2;     // 12 MB
  u16* Qr      = (u16*)w;   w += (size_t)B_SZ * NH * S_LEN * DH * 2;   // 8 MB
  u16* Kr      = (u16*)w;   w += (size_t)B_SZ * NKV * S_LEN * DH * 2;  // 2 MB
  u16* Vt      = (u16*)w;   w += (size_t)B_SZ * NKV * DH * S_LEN * 2;  // 2 MB
  u16* Og      = (u16*)w;                                        // 8 MB

  dim3 tb(32, 8);
  k_cast_x<<<MROWS * DM / (256 * 4), 256, 0, stream>>>(x, Xb);
  k_transpose_w<<<dim3(32, 32), tb, 0, stream>>>(Wq, 1024, Wqkvt);
  k_transpose_w<<<dim3(32, 8),  tb, 0, stream>>>(Wk, 256,  Wqkvt + (size_t)1024 * 1024);
  k_transpose_w<<<dim3(32, 8),  tb, 0, stream>>>(Wv, 256,  Wqkvt + (size_t)1280 * 1024);
  k_transpose_w<<<dim3(32, 32), tb, 0, stream>>>(Wo, 1024, Wot);
  k_prep_small<<<(S_LEN * 32 + 255) / 256, 256, 0, stream>>>(bq, bk, bv, pe, biasq, cs, sn);

  k_gemm<u16><<<dim3(MROWS / 128, NQKVC / 128), 256, 0, stream>>>(
      Xb, Wqkvt, biasq, QKVp, MROWS, NQKVC, DM);

  k_rope_pack<<<MROWS * NQKVC / 256, 256, 0, stream>>>(QKVp, cs, sn, Qr, Kr, Vt);

  k_attn<<<dim3(B_SZ * NH, S_LEN / 64), 256, 0, stream>>>(Qr, Kr, Vt, Og);

  k_gemm<float><<<dim3(MROWS / 128, DM / 128), 256, 0, stream>>>(
      Og, Wot, bo, out, MROWS, DM, DM);
}

// Round 4
// 284.764 us; speedup vs baseline: 1.0606x; 1.0606x over previous
//
#include <hip/hip_runtime.h>
#include <hip/hip_bf16.h>

using f32x4  = __attribute__((ext_vector_type(4))) float;
using short8 = __attribute__((ext_vector_type(8))) short;
using u16    = unsigned short;
using u32    = unsigned int;

#define B_SZ   2
#define S_LEN  2048
#define NH     16
#define NKV    4
#define DH     64
#define DM     1024
#define NQKVC  1536
#define MROWS  4096
// 0.125 * log2(e): scores computed in log2 domain, softmax via exp2
#define QSCALE 0.18033688011112042f

__device__ __forceinline__ u16 f2bf(float f) {
  return __builtin_bit_cast(u16, __float2bfloat16(f));
}
__device__ __forceinline__ float bf2f(u16 b) {
  return __builtin_bit_cast(float, ((u32)b) << 16);
}
__device__ __forceinline__ void gld16(const void* g, void* l) {
  __builtin_amdgcn_global_load_lds((const __attribute__((address_space(1))) u32*)g,
                                   (__attribute__((address_space(3))) u32*)l, 16, 0, 0);
}

// ---------------- cast X fp32 -> bf16 ----------------
__global__ void k_cast_x(const float* __restrict__ x, u16* __restrict__ xb) {
  int i = (blockIdx.x * 256 + threadIdx.x) * 4;
  float4 v = *(const float4*)(x + i);
  ushort4 o;
  o.x = f2bf(v.x); o.y = f2bf(v.y); o.z = f2bf(v.z); o.w = f2bf(v.w);
  *(ushort4*)(xb + i) = o;
}

// ---------------- weight transpose: W[K=1024][ncols] fp32 -> Wt[n][1024] bf16 ----------------
__global__ void k_transpose_w(const float* __restrict__ w, int ncols, u16* __restrict__ wt) {
  __shared__ float t[32][33];
  int k0 = blockIdx.x * 32, n0 = blockIdx.y * 32;
  int tx = threadIdx.x, ty = threadIdx.y; // block (32,8)
#pragma unroll
  for (int j = 0; j < 32; j += 8)
    t[ty + j][tx] = w[(size_t)(k0 + ty + j) * ncols + n0 + tx];
  __syncthreads();
#pragma unroll
  for (int j = 0; j < 32; j += 8)
    wt[(size_t)(n0 + ty + j) * 1024 + k0 + tx] = f2bf(t[tx][ty + j]);
}

// ---------------- bias concat + trig tables ----------------
__global__ void k_prep_small(const float* __restrict__ bq, const float* __restrict__ bk,
                             const float* __restrict__ bv, const float* __restrict__ pe,
                             float* __restrict__ biasqkv, float* __restrict__ cs,
                             float* __restrict__ sn) {
  int i = blockIdx.x * 256 + threadIdx.x;
  if (i < NQKVC)
    biasqkv[i] = (i < 1024) ? bq[i] : (i < 1280 ? bk[i - 1024] : bv[i - 1280]);
  if (i < S_LEN * 32) {
    float a = pe[i];
    cs[i] = cosf(a);
    sn[i] = sinf(a);
  }
}

// ---------------- bf16 MFMA GEMM (m97-style global_load_lds staging) ----------------
template <typename OUT_T>
__global__ __launch_bounds__(256) void k_gemm(const u16* __restrict__ A,
                                              const u16* __restrict__ Bt,
                                              const float* __restrict__ bias,
                                              OUT_T* __restrict__ C,
                                              int M, int N, int K) {
  __shared__ u16 la[128 * 32];  // linear [128 rows][32 bf16], 64B rows
  __shared__ u16 lb[128 * 32];
  const int tid = threadIdx.x;
  const int m0 = blockIdx.x * 128, n0 = blockIdx.y * 128;
  const int lane = tid & 63, wv = tid >> 6;
  const int g = lane >> 4, lr = lane & 15;
  const int wr = wv >> 1, wc = wv & 1;

  // staging geometry: wave issues cover 16 rows x 64B each (64 lanes x 16B)
  const int srow0 = (wv * 2 + 0) * 16 + (lane >> 2);
  const int srow1 = (wv * 2 + 1) * 16 + (lane >> 2);
  const int scol = (lane & 3) * 8;  // u16 units
  const u16* pa0 = A  + (size_t)(m0 + srow0) * K + scol;
  const u16* pa1 = A  + (size_t)(m0 + srow1) * K + scol;
  const u16* pb0 = Bt + (size_t)(n0 + srow0) * K + scol;
  const u16* pb1 = Bt + (size_t)(n0 + srow1) * K + scol;
  u16* lda0 = &la[(wv * 2 + 0) * 512];
  u16* lda1 = &la[(wv * 2 + 1) * 512];
  u16* ldb0 = &lb[(wv * 2 + 0) * 512];
  u16* ldb1 = &lb[(wv * 2 + 1) * 512];

  f32x4 acc[4][4] = {};
  const int nk = K >> 5;
  for (int kt = 0; kt < nk; ++kt) {
    const int ko = kt * 32;
    gld16(pa0 + ko, lda0);
    gld16(pa1 + ko, lda1);
    gld16(pb0 + ko, ldb0);
    gld16(pb1 + ko, ldb1);
    __syncthreads();  // drains vmcnt; LDS tiles ready
    short8 af[4], bfr[4];
#pragma unroll
    for (int m = 0; m < 4; ++m)
      af[m] = *(const short8*)&la[(64 * wr + 16 * m + lr) * 32 + 8 * g];
#pragma unroll
    for (int n = 0; n < 4; ++n)
      bfr[n] = *(const short8*)&lb[(64 * wc + 16 * n + lr) * 32 + 8 * g];
#pragma unroll
    for (int m = 0; m < 4; ++m)
#pragma unroll
      for (int n = 0; n < 4; ++n)
        acc[m][n] = __builtin_amdgcn_mfma_f32_16x16x32_bf16(af[m], bfr[n], acc[m][n], 0, 0, 0);
    __syncthreads();  // all reads done before next stage overwrites
  }

#pragma unroll
  for (int m = 0; m < 4; ++m)
#pragma unroll
    for (int n = 0; n < 4; ++n) {
      const int col = n0 + 64 * wc + 16 * n + lr;
      const float bz = bias[col];
#pragma unroll
      for (int r = 0; r < 4; ++r) {
        const int row = m0 + 64 * wr + 16 * m + 4 * g + r;
        float v = acc[m][n][r] + bz;
        if constexpr (sizeof(OUT_T) == 2) C[(size_t)row * N + col] = f2bf(v);
        else                              C[(size_t)row * N + col] = v;
      }
    }
}

// ---------------- RoPE (Q scaled by QSCALE) + Q/K pack ----------------
// one block per (b,s) row; QKVp bf16 [4096][1536]
__global__ void k_rope_qk(const u16* __restrict__ p, const float* __restrict__ cs,
                          const float* __restrict__ sn, u16* __restrict__ Qr,
                          u16* __restrict__ Kr) {
  const int row = blockIdx.x;
  const int b = row >> 11, s = row & 2047;
  const u16* pr = p + (size_t)row * NQKVC;
  const float* crow = cs + s * 32;
  const float* srow = sn + s * 32;
  const int tid = threadIdx.x;
#pragma unroll
  for (int it = 0; it < 4; ++it) {
    int c = it * 256 + tid;
    int h = c >> 6, d = c & 63, j = d & 31;
    float x = bf2f(pr[c]);
    float y = bf2f(pr[c ^ 32]);
    float o = (x * crow[j] + (d < 32 ? -y : y) * srow[j]) * QSCALE;
    Qr[((size_t)(b * NH + h) * S_LEN + s) * DH + d] = f2bf(o);
  }
  {
    int c = 1024 + tid;
    int kvh = tid >> 6, d = tid & 63, j = d & 31;
    float x = bf2f(pr[c]);
    float y = bf2f(pr[c ^ 32]);
    float o = x * crow[j] + (d < 32 ? -y : y) * srow[j];
    Kr[((size_t)(b * NKV + kvh) * S_LEN + s) * DH + d] = f2bf(o);
  }
}

// ---------------- V pack: QKVp cols [1280,1536) -> Vt[B][Kv][64][S] (coalesced transpose) ----------------
__global__ void k_vpack(const u16* __restrict__ p, u16* __restrict__ Vt) {
  __shared__ u16 t[32][33];
  const int st = blockIdx.x * 32;  // s tile
  const int dt = blockIdx.y * 32;  // d tile
  const int bkv = blockIdx.z;
  const int b = bkv >> 2, kv = bkv & 3;
  const int tx = threadIdx.x, ty = threadIdx.y;  // (32,8)
#pragma unroll
  for (int j = 0; j < 32; j += 8)
    t[ty + j][tx] = p[(size_t)(b * S_LEN + st + ty + j) * NQKVC + 1280 + kv * 64 + dt + tx];
  __syncthreads();
#pragma unroll
  for (int j = 0; j < 32; j += 8)
    Vt[((size_t)(b * NKV + kv) * DH + dt + ty + j) * S_LEN + st + tx] = t[tx][ty + j];
}

// ---------------- causal GQA flash attention (swapped-operand, lane-local rows) ----------------
// grid (B*H, 16), block 512. Waves 0-3: q-tile yb; waves 4-7: q-tile 31-yb (load balance).
// Each wave owns 16 q rows; lane's q = q0 + (lane&15). Scores/O are lane-local per q.
__global__ __launch_bounds__(512, 4) void k_attn(const u16* __restrict__ Qr,
                                                 const u16* __restrict__ Kr,
                                                 const u16* __restrict__ Vt,
                                                 u16* __restrict__ Og) {
  __shared__ u16 plds[8][16][72];  // per-wave P[q16][key64], padded row stride
  const int tid = threadIdx.x, wv = tid >> 6, lane = tid & 63;
  const int g = lane >> 4, lr = lane & 15;
  const int bh = blockIdx.x;
  const int b = bh >> 4, h = bh & 15, kv = h >> 2;
  const int qt = (wv < 4) ? (int)blockIdx.y : (31 - (int)blockIdx.y);
  const int q0 = qt * 64 + (wv & 3) * 16;

  const u16* Qbase = Qr + ((size_t)(b * NH + h) * S_LEN + q0) * DH;
  const u16* Kbase = Kr + (size_t)(b * NKV + kv) * S_LEN * DH;
  const u16* Vbase = Vt + (size_t)(b * NKV + kv) * DH * S_LEN;

  short8 qf0 = *(const short8*)(Qbase + lr * DH + 8 * g);       // d 0..31
  short8 qf1 = *(const short8*)(Qbase + lr * DH + 32 + 8 * g);  // d 32..63

  float m = -1e30f, l = 0.f;
  f32x4 accO[4] = {};   // O^T[d = 16t+4g+r][q = lr]
  const f32x4 z = {};
  u16* prow = &plds[wv][lr][0];

  const int myq = q0 + lr;
  const int kend = q0 + 16;  // keys [0, kend); tail keys masked causally
  for (int kb = 0; kb < kend; kb += 64) {
    // ---- QK^T (swapped: A=K rows=keys, B=Q cols=q) ----
    f32x4 s[4];
#pragma unroll
    for (int t = 0; t < 4; ++t) {
      const u16* kp = Kbase + (size_t)(kb + 16 * t + lr) * DH;
      short8 k0 = *(const short8*)(kp + 8 * g);
      short8 k1 = *(const short8*)(kp + 32 + 8 * g);
      s[t] = __builtin_amdgcn_mfma_f32_16x16x32_bf16(k0, qf0, z, 0, 0, 0);
      s[t] = __builtin_amdgcn_mfma_f32_16x16x32_bf16(k1, qf1, s[t], 0, 0, 0);
    }
    // ---- causal mask (diagonal 64-block only; also covers the ragged tail) ----
    if (kb + 63 > q0) {
#pragma unroll
      for (int t = 0; t < 4; ++t)
#pragma unroll
        for (int r = 0; r < 4; ++r)
          if (kb + 16 * t + 4 * g + r > myq) s[t][r] = -1e30f;
    }
    // ---- online softmax (log2 domain), lane-local row ----
    float a0 = fmaxf(fmaxf(s[0][0], s[0][1]), fmaxf(s[0][2], s[0][3]));
    float a1 = fmaxf(fmaxf(s[1][0], s[1][1]), fmaxf(s[1][2], s[1][3]));
    float a2 = fmaxf(fmaxf(s[2][0], s[2][1]), fmaxf(s[2][2], s[2][3]));
    float a3 = fmaxf(fmaxf(s[3][0], s[3][1]), fmaxf(s[3][2], s[3][3]));
    float tm = fmaxf(fmaxf(a0, a1), fmaxf(a2, a3));
    tm = fmaxf(tm, __shfl_xor(tm, 16));
    tm = fmaxf(tm, __shfl_xor(tm, 32));
    if (__any(tm > m)) {           // T13: skip rescale when max unchanged
      float mn = fmaxf(tm, m);
      float al = __builtin_exp2f(m - mn);
      m = mn;
      l *= al;
#pragma unroll
      for (int t = 0; t < 4; ++t) {
        accO[t][0] *= al; accO[t][1] *= al; accO[t][2] *= al; accO[t][3] *= al;
      }
    }
    float rs = 0.f;
#pragma unroll
    for (int t = 0; t < 4; ++t)
#pragma unroll
      for (int r = 0; r < 4; ++r) {
        float e = __builtin_exp2f(s[t][r] - m);
        s[t][r] = e;
        rs += e;
      }
    rs += __shfl_xor(rs, 16);
    rs += __shfl_xor(rs, 32);
    l += rs;
    // ---- P -> LDS (row q=lr, cols = keys), b64 writes ----
#pragma unroll
    for (int t = 0; t < 4; ++t) {
      u32 lo = (u32)f2bf(s[t][0]) | ((u32)f2bf(s[t][1]) << 16);
      u32 hi = (u32)f2bf(s[t][2]) | ((u32)f2bf(s[t][3]) << 16);
      uint2 w2; w2.x = lo; w2.y = hi;
      *(uint2*)(prow + 16 * t + 4 * g) = w2;
    }
    // ---- PV (swapped: A=V^T rows=d, B=P^T cols=q) ----
#pragma unroll
    for (int hh = 0; hh < 2; ++hh) {
      short8 pb = *(const short8*)(prow + 32 * hh + 8 * g);
#pragma unroll
      for (int t = 0; t < 4; ++t) {
        short8 vf = *(const short8*)(Vbase + (size_t)(16 * t + lr) * S_LEN + kb + 32 * hh + 8 * g);
        accO[t] = __builtin_amdgcn_mfma_f32_16x16x32_bf16(vf, pb, accO[t], 0, 0, 0);
      }
    }
  }

  const float inv = 1.0f / l;
  u16* orow = Og + ((size_t)(b * S_LEN + q0 + lr)) * DM + h * DH;
#pragma unroll
  for (int t = 0; t < 4; ++t) {
    ushort4 o;
    o.x = f2bf(accO[t][0] * inv);
    o.y = f2bf(accO[t][1] * inv);
    o.z = f2bf(accO[t][2] * inv);
    o.w = f2bf(accO[t][3] * inv);
    *(ushort4*)(orow + 16 * t + 4 * g) = o;
  }
}

extern "C" void kernel_launch(void* const* d_in, const int* in_sizes, int n_in,
                              void* d_out, int out_size, void* d_ws, size_t ws_size,
                              hipStream_t stream) {
  const float* x  = (const float*)d_in[0];
  const float* pe = (const float*)d_in[1];
  const float* Wq = (const float*)d_in[2];
  const float* bq = (const float*)d_in[3];
  const float* Wk = (const float*)d_in[4];
  const float* bk = (const float*)d_in[5];
  const float* Wv = (const float*)d_in[6];
  const float* bv = (const float*)d_in[7];
  const float* Wo = (const float*)d_in[8];
  const float* bo = (const float*)d_in[9];
  float* out = (float*)d_out;

  char* w = (char*)d_ws;
  u16* Xb      = (u16*)w;   w += (size_t)MROWS * DM * 2;
  u16* Wqkvt   = (u16*)w;   w += (size_t)NQKVC * DM * 2;
  u16* Wot     = (u16*)w;   w += (size_t)DM * DM * 2;
  float* biasq = (float*)w; w += NQKVC * 4;
  float* cs    = (float*)w; w += S_LEN * 32 * 4;
  float* sn    = (float*)w; w += S_LEN * 32 * 4;
  u16* QKVp    = (u16*)w;   w += (size_t)MROWS * NQKVC * 2;
  u16* Qr      = (u16*)w;   w += (size_t)B_SZ * NH * S_LEN * DH * 2;
  u16* Kr      = (u16*)w;   w += (size_t)B_SZ * NKV * S_LEN * DH * 2;
  u16* Vt      = (u16*)w;   w += (size_t)B_SZ * NKV * DH * S_LEN * 2;
  u16* Og      = (u16*)w;

  dim3 tb(32, 8);
  k_cast_x<<<MROWS * DM / (256 * 4), 256, 0, stream>>>(x, Xb);
  k_transpose_w<<<dim3(32, 32), tb, 0, stream>>>(Wq, 1024, Wqkvt);
  k_transpose_w<<<dim3(32, 8),  tb, 0, stream>>>(Wk, 256,  Wqkvt + (size_t)1024 * 1024);
  k_transpose_w<<<dim3(32, 8),  tb, 0, stream>>>(Wv, 256,  Wqkvt + (size_t)1280 * 1024);
  k_transpose_w<<<dim3(32, 32), tb, 0, stream>>>(Wo, 1024, Wot);
  k_prep_small<<<(S_LEN * 32 + 255) / 256, 256, 0, stream>>>(bq, bk, bv, pe, biasq, cs, sn);

  k_gemm<u16><<<dim3(MROWS / 128, NQKVC / 128), 256, 0, stream>>>(
      Xb, Wqkvt, biasq, QKVp, MROWS, NQKVC, DM);

  k_rope_qk<<<MROWS, 256, 0, stream>>>(QKVp, cs, sn, Qr, Kr);
  k_vpack<<<dim3(S_LEN / 32, DH / 32, B_SZ * NKV), tb, 0, stream>>>(QKVp, Vt);

  k_attn<<<dim3(B_SZ * NH, 16), 512, 0, stream>>>(Qr, Kr, Vt, Og);

  k_gemm<float><<<dim3(MROWS / 128, DM / 128), 256, 0, stream>>>(
      Og, Wot, bo, out, MROWS, DM, DM);
}